// Round 10
// baseline (508.414 us; speedup 1.0000x reference)
//
#include <hip/hip_runtime.h>
#include <math.h>

#define NCn 64            // chunks per batch
#define NCHUNK 256        // total chunks (B=4)
#define NROW 8192         // B*T

__device__ __forceinline__ float elu1(float v) {
    return (v > 0.f) ? v + 1.f : expf(v);
}

// ---------------------------------------------------------------------------
// Hand-rolled grid barrier. Requires ALL blocks resident (guaranteed:
// grid=1024 = 4 blocks/CU x 256 CU via launch_bounds(256,4) + 38.4KB LDS).
// cnt is zeroed by hipMemsetAsync before every launch (single-use counter).
// Device-scope atomics + threadfence give cross-XCD release/acquire.
// ---------------------------------------------------------------------------
__device__ __forceinline__ void grid_barrier(unsigned* cnt, unsigned target) {
    __syncthreads();
    if (threadIdx.x == 0) {
        __threadfence();                       // release: prior writes visible
        atomicAdd(cnt, 1u);
        while (atomicAdd(cnt, 0u) < target)    // device-scope atomic read
            __builtin_amdgcn_s_sleep(2);
        __threadfence();                       // acquire
    }
    __syncthreads();
}

// ===========================================================================
// Phase bodies (byte-identical math to the measured R7 kernels)
// ===========================================================================

// qkv = x @ W^T + b ; q,k <- elu+1. 64x64 tile, 4x4 micro-tile, strided cols.
__device__ __forceinline__ void qkv_phase(
    const float* __restrict__ x, const float* __restrict__ W,
    const float* __restrict__ bias,
    float* __restrict__ qb, float* __restrict__ kb, float* __restrict__ vb,
    float* sX, float* sW, int m0, int cbase)
{
    const int tid = threadIdx.x;
    const int ty = tid >> 4, tx = tid & 15;
    const int r0 = ty * 4;

    float acc[4][4];
#pragma unroll
    for (int r = 0; r < 4; ++r)
#pragma unroll
        for (int c = 0; c < 4; ++c) acc[r][c] = 0.f;

    for (int kc = 0; kc < 4; ++kc) {
        __syncthreads();
        {
            int idx = tid;
#pragma unroll
            for (int i = 0; i < 2; ++i, idx += 256) {
                const int row = idx >> 3, f = idx & 7;
                *(float4*)&sX[row * 36 + f * 4] =
                    *(const float4*)(x + (size_t)(m0 + row) * 128 + kc * 32 + f * 4);
                *(float4*)&sW[row * 36 + f * 4] =
                    *(const float4*)(W + (size_t)(cbase + row) * 128 + kc * 32 + f * 4);
            }
        }
        __syncthreads();

#pragma unroll
        for (int k4 = 0; k4 < 8; ++k4) {
            float4 xr[4], wr[4];
#pragma unroll
            for (int r = 0; r < 4; ++r)
                xr[r] = *(const float4*)&sX[(r0 + r) * 36 + k4 * 4];
#pragma unroll
            for (int c = 0; c < 4; ++c)
                wr[c] = *(const float4*)&sW[(tx + 16 * c) * 36 + k4 * 4];
#pragma unroll
            for (int r = 0; r < 4; ++r)
#pragma unroll
                for (int c = 0; c < 4; ++c)
                    acc[r][c] += xr[r].x * wr[c].x + xr[r].y * wr[c].y
                               + xr[r].z * wr[c].z + xr[r].w * wr[c].w;
        }
    }

    float* dst; int coff; bool act;
    if (cbase < 128)      { dst = qb; coff = cbase;       act = true;  }
    else if (cbase < 256) { dst = kb; coff = cbase - 128; act = true;  }
    else                  { dst = vb; coff = cbase - 256; act = false; }

    float bb[4];
#pragma unroll
    for (int c = 0; c < 4; ++c) bb[c] = bias[cbase + tx + 16 * c];

#pragma unroll
    for (int r = 0; r < 4; ++r) {
        float* drow = dst + (size_t)(m0 + r0 + r) * 128 + coff + tx;
#pragma unroll
        for (int c = 0; c < 4; ++c) {
            float o = acc[r][c] + bb[c];
            if (act) o = elu1(o);
            drow[16 * c] = o;
        }
    }
}

// cs: b<512 half-K^T V ; b in [512,768): causal scores + rowsum + colsum(K)
__device__ __forceinline__ void cs_phase(
    const float* __restrict__ qb, const float* __restrict__ kb,
    const float* __restrict__ vb,
    float* __restrict__ kvb, float* __restrict__ ksb,
    float* __restrict__ scb, float* __restrict__ rsb,
    float* smem, int b)
{
    const int tid = threadIdx.x;

    if (b < 512) {
        const int cb = b >> 1, jh = b & 1;
        float* sK  = smem;          // [32][132]
        float* sVh = smem + 4224;   // [32][68]
        {
            const float4* kg = (const float4*)(kb + (size_t)cb * 4096);
#pragma unroll
            for (int i = 0; i < 4; ++i) {
                int idx = tid + i * 256;
                int r = idx >> 5, c4 = idx & 31;
                *(float4*)&sK[r * 132 + c4 * 4] = kg[idx];
            }
            const float* vg = vb + (size_t)cb * 4096 + jh * 64;
#pragma unroll
            for (int i = 0; i < 2; ++i) {
                int idx = tid + i * 256;
                int r = idx >> 4, c4 = idx & 15;
                *(float4*)&sVh[r * 68 + c4 * 4] = *(const float4*)(vg + r * 128 + c4 * 4);
            }
        }
        __syncthreads();

        const int i0 = (tid >> 4) * 8;
        const int j0 = (tid & 15) * 4;
        float acc[8][4];
#pragma unroll
        for (int a = 0; a < 8; ++a)
#pragma unroll
            for (int c = 0; c < 4; ++c) acc[a][c] = 0.f;

#pragma unroll 2
        for (int t = 0; t < 32; ++t) {
            float4 ka  = *(const float4*)&sK[t * 132 + i0];
            float4 kb4 = *(const float4*)&sK[t * 132 + i0 + 4];
            float4 vv  = *(const float4*)&sVh[t * 68 + j0];
            float kk[8] = {ka.x, ka.y, ka.z, ka.w, kb4.x, kb4.y, kb4.z, kb4.w};
#pragma unroll
            for (int a = 0; a < 8; ++a) {
                acc[a][0] += kk[a] * vv.x;
                acc[a][1] += kk[a] * vv.y;
                acc[a][2] += kk[a] * vv.z;
                acc[a][3] += kk[a] * vv.w;
            }
        }
        float* outp = kvb + (size_t)cb * 16384 + jh * 64;
#pragma unroll
        for (int a = 0; a < 8; ++a)
            *(float4*)&outp[(i0 + a) * 128 + j0] =
                make_float4(acc[a][0], acc[a][1], acc[a][2], acc[a][3]);
    } else if (b < 768) {
        const int cb = b - 512;
        float* sQ  = smem;          // [32][132]
        float* sK2 = smem + 4224;   // [32][132]
        float* sSc = smem + 8448;   // [32][36]
        {
            const float4* qg = (const float4*)(qb + (size_t)cb * 4096);
            const float4* kg = (const float4*)(kb + (size_t)cb * 4096);
#pragma unroll
            for (int i = 0; i < 4; ++i) {
                int idx = tid + i * 256;
                int r = idx >> 5, c4 = idx & 31;
                *(float4*)&sQ[r * 132 + c4 * 4]  = qg[idx];
                *(float4*)&sK2[r * 132 + c4 * 4] = kg[idx];
            }
        }
        __syncthreads();

        const int ta  = tid >> 3;
        const int tp0 = (tid & 7) * 4;
        float d[4] = {0.f, 0.f, 0.f, 0.f};
#pragma unroll 4
        for (int k4 = 0; k4 < 32; ++k4) {
            float4 qa = *(const float4*)&sQ[ta * 132 + k4 * 4];
#pragma unroll
            for (int u = 0; u < 4; ++u) {
                float4 kv = *(const float4*)&sK2[(tp0 + u) * 132 + k4 * 4];
                d[u] += qa.x * kv.x + qa.y * kv.y + qa.z * kv.z + qa.w * kv.w;
            }
        }
        float4 m;
        m.x = (tp0 + 0 <= ta) ? d[0] : 0.f;
        m.y = (tp0 + 1 <= ta) ? d[1] : 0.f;
        m.z = (tp0 + 2 <= ta) ? d[2] : 0.f;
        m.w = (tp0 + 3 <= ta) ? d[3] : 0.f;
        *(float4*)&sSc[ta * 36 + tp0] = m;
        *(float4*)(scb + (size_t)cb * 1024 + ta * 32 + tp0) = m;
        __syncthreads();

        if (tid < 32) {
            float s = 0.f;
#pragma unroll
            for (int tp = 0; tp < 32; ++tp) s += sSc[tid * 36 + tp];
            rsb[cb * 32 + tid] = s;
        } else if (tid >= 64 && tid < 192) {
            const int i = tid - 64;
            float s = 0.f;
#pragma unroll
            for (int t = 0; t < 32; ++t) s += sK2[t * 132 + i];
            ksb[cb * 128 + i] = s;
        }
    }
}

// prefix: exclusive scan over 64 chunks/batch, blocks [0,258)
__device__ __forceinline__ void prefix_phase(
    float* __restrict__ kvb, float* __restrict__ ksb, int blk)
{
    const int tid = threadIdx.x;
    if (blk < 256) {
        const int L = blk * 256 + tid;
        const int b = L >> 14, ij = L & 16383;
        float* p = kvb + (size_t)b * NCn * 16384 + ij;
        float run = 0.f;
        for (int g = 0; g < 4; ++g) {
            float buf[16];
#pragma unroll
            for (int j = 0; j < 16; ++j) buf[j] = p[(size_t)(g * 16 + j) * 16384];
#pragma unroll
            for (int j = 0; j < 16; ++j) {
                p[(size_t)(g * 16 + j) * 16384] = run;
                run += buf[j];
            }
        }
    } else if (blk < 258) {
        const int L = (blk - 256) * 256 + tid;
        const int b = L >> 7, i = L & 127;
        float* p = ksb + (size_t)b * NCn * 128 + i;
        float run = 0.f;
        for (int g = 0; g < 4; ++g) {
            float buf[16];
#pragma unroll
            for (int j = 0; j < 16; ++j) buf[j] = p[(size_t)(g * 16 + j) * 128];
#pragma unroll
            for (int j = 0; j < 16; ++j) {
                p[(size_t)(g * 16 + j) * 128] = run;
                run += buf[j];
            }
        }
    }
}

// out = (Q @ S_prefix + Sc @ V) / den
__device__ __forceinline__ void out_phase(
    const float* __restrict__ qb, const float* __restrict__ vb,
    const float* __restrict__ kvb, const float* __restrict__ ksb,
    const float* __restrict__ scb, const float* __restrict__ rsb,
    float* __restrict__ out, float* smem, int cb, int ch)
{
    float* sQ  = smem;           // 32*132 = 4224
    float* sVs = smem + 4224;    // 32*36  = 1152
    float* sSc = smem + 5376;    // 32*36  = 1152
    float* sKp = smem + 6528;    // 128
    float* sDen = smem + 6656;   // 32

    const int tid = threadIdx.x;

    {
        const float4* qg = (const float4*)(qb + (size_t)cb * 4096);
#pragma unroll
        for (int i = 0; i < 4; ++i) {
            int idx = tid + i * 256;
            int r = idx >> 5, c4 = idx & 31;
            *(float4*)&sQ[r * 132 + c4 * 4] = qg[idx];
        }
        {
            int r = tid >> 3, c4 = tid & 7;
            *(float4*)&sVs[r * 36 + c4 * 4] =
                *(const float4*)(vb + (size_t)cb * 4096 + r * 128 + ch * 32 + c4 * 4);
            *(float4*)&sSc[r * 36 + c4 * 4] =
                *(const float4*)(scb + (size_t)cb * 1024 + tid * 4);
        }
        if (tid < 128) sKp[tid] = ksb[cb * 128 + tid];
    }
    __syncthreads();

    if (tid < 32) {
        float d = 0.f;
#pragma unroll
        for (int k4 = 0; k4 < 32; ++k4) {
            float4 a  = *(const float4*)&sQ[tid * 132 + k4 * 4];
            float4 b2 = *(const float4*)&sKp[k4 * 4];
            d += a.x * b2.x + a.y * b2.y + a.z * b2.z + a.w * b2.w;
        }
        sDen[tid] = d + rsb[cb * 32 + tid] + 1e-6f;
    }

    const int row = tid >> 3;
    const int c4  = tid & 7;
    const float* Sg = kvb + (size_t)cb * 16384 + ch * 32 + c4 * 4;

    float a0 = 0.f, a1 = 0.f, a2 = 0.f, a3 = 0.f;
#pragma unroll 8
    for (int k = 0; k < 128; ++k) {
        const float qv = sQ[row * 132 + k];
        float4 s = *(const float4*)(Sg + (size_t)k * 128);
        a0 += qv * s.x; a1 += qv * s.y; a2 += qv * s.z; a3 += qv * s.w;
    }
#pragma unroll 8
    for (int tp = 0; tp < 32; ++tp) {
        const float sc = sSc[row * 36 + tp];
        float4 v = *(const float4*)&sVs[tp * 36 + c4 * 4];
        a0 += sc * v.x; a1 += sc * v.y; a2 += sc * v.z; a3 += sc * v.w;
    }
    __syncthreads();

    const float dv = sDen[row];
    *(float4*)(out + ((size_t)cb * 32 + row) * 128 + ch * 32 + c4 * 4) =
        make_float4(a0 / dv, a1 / dv, a2 / dv, a3 / dv);
}

// ===========================================================================
// Fused kernel: plain launch, grid 1024 x 256, 4 blocks/CU (guaranteed by
// launch_bounds(256,4) VGPR cap + 38.4 KB LDS), hand-rolled grid barriers.
// ===========================================================================
__global__ __launch_bounds__(256, 4) void fused_kernel(
    const float* __restrict__ x, const float* __restrict__ W,
    const float* __restrict__ bias,
    float* __restrict__ qb, float* __restrict__ kb, float* __restrict__ vb,
    float* __restrict__ kvb, float* __restrict__ ksb,
    float* __restrict__ scb, float* __restrict__ rsb,
    float* __restrict__ out, unsigned* __restrict__ bar)
{
    __shared__ __align__(16) float smem[9600];   // 38.4 KB (union of phases)
    const int blk = blockIdx.x;

    if (blk < 768)
        qkv_phase(x, W, bias, qb, kb, vb, smem, smem + 2304,
                  (blk & 127) * 64, (blk >> 7) * 64);
    grid_barrier(bar + 0, 1024u);

    cs_phase(qb, kb, vb, kvb, ksb, scb, rsb, smem, blk);
    grid_barrier(bar + 16, 1024u);

    prefix_phase(kvb, ksb, blk);
    grid_barrier(bar + 32, 1024u);

    out_phase(qb, vb, kvb, ksb, scb, rsb, out, smem, blk >> 2, blk & 3);
}

// ===========================================================================
extern "C" void kernel_launch(void* const* d_in, const int* in_sizes, int n_in,
                              void* d_out, int out_size, void* d_ws, size_t ws_size,
                              hipStream_t stream)
{
    const float* x    = (const float*)d_in[0];   // (B,T,D)
    const float* W    = (const float*)d_in[1];   // (3D, D)
    const float* bias = (const float*)d_in[2];   // (3D,)
    float* out = (float*)d_out;                  // (B,T,D)

    float* ws  = (float*)d_ws;
    float* qb  = ws;                       // 1,048,576 floats
    float* kb  = ws + 1048576;             // 1,048,576
    float* vb  = ws + 2097152;             // 1,048,576
    float* kvb = ws + 3145728;             // 4,194,304
    float* ksb = ws + 7340032;             // 32,768
    float* scb = ws + 7372800;             // 262,144
    float* rsb = ws + 7634944;             // 8,192
    unsigned* bar = (unsigned*)(ws + 7643136);   // 48 counters (3 used, spaced)

    hipMemsetAsync(bar, 0, 48 * sizeof(unsigned), stream);
    fused_kernel<<<1024, 256, 0, stream>>>(x, W, bias, qb, kb, vb, kvb, ksb,
                                           scb, rsb, out, bar);
}

// Round 11
// 349.201 us; speedup vs baseline: 1.4559x; 1.4559x over previous
//
#include <hip/hip_runtime.h>
#include <math.h>

#define NCn 64            // chunks per batch
#define NCHUNK 256        // total chunks (B=4)
#define NROW 8192         // B*T

__device__ __forceinline__ float elu1(float v) {
    return (v > 0.f) ? v + 1.f : expf(v);
}

// ---------------------------------------------------------------------------
// Low-contention grid barrier. All 1024 blocks resident (launch_bounds(256,4)
// + 38.4KB LDS -> exactly 4 blocks/CU x 256 CU). Arrivals spread over 16
// counters (64B apart): ~64 serialized RMWs per counter. Polling uses
// relaxed agent-scope atomic LOADS (no RMW -> concurrent, no coherence-point
// serialization; R10's RMW-poll cost ~300us). Fence structure identical to
// the R10-passing version: release fence before arrival, acquire after poll.
// Counters zeroed by hipMemsetAsync before every launch.
// ---------------------------------------------------------------------------
__device__ __forceinline__ void grid_barrier(unsigned* base, unsigned per_cnt,
                                             int blk) {
    __syncthreads();
    const int tid = threadIdx.x;
    if (tid == 0) {
        __threadfence();                                   // release
        atomicAdd(base + (blk & 15) * 16, 1u);
    }
    if (tid < 16) {
        unsigned* c = base + tid * 16;
        while (__hip_atomic_load(c, __ATOMIC_RELAXED,
                                 __HIP_MEMORY_SCOPE_AGENT) < per_cnt)
            __builtin_amdgcn_s_sleep(8);
        if (tid == 0) __threadfence();                     // acquire
    }
    __syncthreads();
}

// ===========================================================================
// Phase bodies (byte-identical math to the measured R7/R10 kernels)
// ===========================================================================

// qkv = x @ W^T + b ; q,k <- elu+1. 64x64 tile, 4x4 micro-tile, strided cols.
__device__ __forceinline__ void qkv_phase(
    const float* __restrict__ x, const float* __restrict__ W,
    const float* __restrict__ bias,
    float* __restrict__ qb, float* __restrict__ kb, float* __restrict__ vb,
    float* sX, float* sW, int m0, int cbase)
{
    const int tid = threadIdx.x;
    const int ty = tid >> 4, tx = tid & 15;
    const int r0 = ty * 4;

    float acc[4][4];
#pragma unroll
    for (int r = 0; r < 4; ++r)
#pragma unroll
        for (int c = 0; c < 4; ++c) acc[r][c] = 0.f;

    for (int kc = 0; kc < 4; ++kc) {
        __syncthreads();
        {
            int idx = tid;
#pragma unroll
            for (int i = 0; i < 2; ++i, idx += 256) {
                const int row = idx >> 3, f = idx & 7;
                *(float4*)&sX[row * 36 + f * 4] =
                    *(const float4*)(x + (size_t)(m0 + row) * 128 + kc * 32 + f * 4);
                *(float4*)&sW[row * 36 + f * 4] =
                    *(const float4*)(W + (size_t)(cbase + row) * 128 + kc * 32 + f * 4);
            }
        }
        __syncthreads();

#pragma unroll
        for (int k4 = 0; k4 < 8; ++k4) {
            float4 xr[4], wr[4];
#pragma unroll
            for (int r = 0; r < 4; ++r)
                xr[r] = *(const float4*)&sX[(r0 + r) * 36 + k4 * 4];
#pragma unroll
            for (int c = 0; c < 4; ++c)
                wr[c] = *(const float4*)&sW[(tx + 16 * c) * 36 + k4 * 4];
#pragma unroll
            for (int r = 0; r < 4; ++r)
#pragma unroll
                for (int c = 0; c < 4; ++c)
                    acc[r][c] += xr[r].x * wr[c].x + xr[r].y * wr[c].y
                               + xr[r].z * wr[c].z + xr[r].w * wr[c].w;
        }
    }

    float* dst; int coff; bool act;
    if (cbase < 128)      { dst = qb; coff = cbase;       act = true;  }
    else if (cbase < 256) { dst = kb; coff = cbase - 128; act = true;  }
    else                  { dst = vb; coff = cbase - 256; act = false; }

    float bb[4];
#pragma unroll
    for (int c = 0; c < 4; ++c) bb[c] = bias[cbase + tx + 16 * c];

#pragma unroll
    for (int r = 0; r < 4; ++r) {
        float* drow = dst + (size_t)(m0 + r0 + r) * 128 + coff + tx;
#pragma unroll
        for (int c = 0; c < 4; ++c) {
            float o = acc[r][c] + bb[c];
            if (act) o = elu1(o);
            drow[16 * c] = o;
        }
    }
}

// cs: b<512 half-K^T V ; b in [512,768): causal scores + rowsum + colsum(K)
__device__ __forceinline__ void cs_phase(
    const float* __restrict__ qb, const float* __restrict__ kb,
    const float* __restrict__ vb,
    float* __restrict__ kvb, float* __restrict__ ksb,
    float* __restrict__ scb, float* __restrict__ rsb,
    float* smem, int b)
{
    const int tid = threadIdx.x;

    if (b < 512) {
        const int cb = b >> 1, jh = b & 1;
        float* sK  = smem;          // [32][132]
        float* sVh = smem + 4224;   // [32][68]
        {
            const float4* kg = (const float4*)(kb + (size_t)cb * 4096);
#pragma unroll
            for (int i = 0; i < 4; ++i) {
                int idx = tid + i * 256;
                int r = idx >> 5, c4 = idx & 31;
                *(float4*)&sK[r * 132 + c4 * 4] = kg[idx];
            }
            const float* vg = vb + (size_t)cb * 4096 + jh * 64;
#pragma unroll
            for (int i = 0; i < 2; ++i) {
                int idx = tid + i * 256;
                int r = idx >> 4, c4 = idx & 15;
                *(float4*)&sVh[r * 68 + c4 * 4] = *(const float4*)(vg + r * 128 + c4 * 4);
            }
        }
        __syncthreads();

        const int i0 = (tid >> 4) * 8;
        const int j0 = (tid & 15) * 4;
        float acc[8][4];
#pragma unroll
        for (int a = 0; a < 8; ++a)
#pragma unroll
            for (int c = 0; c < 4; ++c) acc[a][c] = 0.f;

#pragma unroll 2
        for (int t = 0; t < 32; ++t) {
            float4 ka  = *(const float4*)&sK[t * 132 + i0];
            float4 kb4 = *(const float4*)&sK[t * 132 + i0 + 4];
            float4 vv  = *(const float4*)&sVh[t * 68 + j0];
            float kk[8] = {ka.x, ka.y, ka.z, ka.w, kb4.x, kb4.y, kb4.z, kb4.w};
#pragma unroll
            for (int a = 0; a < 8; ++a) {
                acc[a][0] += kk[a] * vv.x;
                acc[a][1] += kk[a] * vv.y;
                acc[a][2] += kk[a] * vv.z;
                acc[a][3] += kk[a] * vv.w;
            }
        }
        float* outp = kvb + (size_t)cb * 16384 + jh * 64;
#pragma unroll
        for (int a = 0; a < 8; ++a)
            *(float4*)&outp[(i0 + a) * 128 + j0] =
                make_float4(acc[a][0], acc[a][1], acc[a][2], acc[a][3]);
    } else if (b < 768) {
        const int cb = b - 512;
        float* sQ  = smem;          // [32][132]
        float* sK2 = smem + 4224;   // [32][132]
        float* sSc = smem + 8448;   // [32][36]
        {
            const float4* qg = (const float4*)(qb + (size_t)cb * 4096);
            const float4* kg = (const float4*)(kb + (size_t)cb * 4096);
#pragma unroll
            for (int i = 0; i < 4; ++i) {
                int idx = tid + i * 256;
                int r = idx >> 5, c4 = idx & 31;
                *(float4*)&sQ[r * 132 + c4 * 4]  = qg[idx];
                *(float4*)&sK2[r * 132 + c4 * 4] = kg[idx];
            }
        }
        __syncthreads();

        const int ta  = tid >> 3;
        const int tp0 = (tid & 7) * 4;
        float d[4] = {0.f, 0.f, 0.f, 0.f};
#pragma unroll 4
        for (int k4 = 0; k4 < 32; ++k4) {
            float4 qa = *(const float4*)&sQ[ta * 132 + k4 * 4];
#pragma unroll
            for (int u = 0; u < 4; ++u) {
                float4 kv = *(const float4*)&sK2[(tp0 + u) * 132 + k4 * 4];
                d[u] += qa.x * kv.x + qa.y * kv.y + qa.z * kv.z + qa.w * kv.w;
            }
        }
        float4 m;
        m.x = (tp0 + 0 <= ta) ? d[0] : 0.f;
        m.y = (tp0 + 1 <= ta) ? d[1] : 0.f;
        m.z = (tp0 + 2 <= ta) ? d[2] : 0.f;
        m.w = (tp0 + 3 <= ta) ? d[3] : 0.f;
        *(float4*)&sSc[ta * 36 + tp0] = m;
        *(float4*)(scb + (size_t)cb * 1024 + ta * 32 + tp0) = m;
        __syncthreads();

        if (tid < 32) {
            float s = 0.f;
#pragma unroll
            for (int tp = 0; tp < 32; ++tp) s += sSc[tid * 36 + tp];
            rsb[cb * 32 + tid] = s;
        } else if (tid >= 64 && tid < 192) {
            const int i = tid - 64;
            float s = 0.f;
#pragma unroll
            for (int t = 0; t < 32; ++t) s += sK2[t * 132 + i];
            ksb[cb * 128 + i] = s;
        }
    }
}

// prefix: exclusive scan over 64 chunks/batch, blocks [0,258)
__device__ __forceinline__ void prefix_phase(
    float* __restrict__ kvb, float* __restrict__ ksb, int blk)
{
    const int tid = threadIdx.x;
    if (blk < 256) {
        const int L = blk * 256 + tid;
        const int b = L >> 14, ij = L & 16383;
        float* p = kvb + (size_t)b * NCn * 16384 + ij;
        float run = 0.f;
        for (int g = 0; g < 4; ++g) {
            float buf[16];
#pragma unroll
            for (int j = 0; j < 16; ++j) buf[j] = p[(size_t)(g * 16 + j) * 16384];
#pragma unroll
            for (int j = 0; j < 16; ++j) {
                p[(size_t)(g * 16 + j) * 16384] = run;
                run += buf[j];
            }
        }
    } else if (blk < 258) {
        const int L = (blk - 256) * 256 + tid;
        const int b = L >> 7, i = L & 127;
        float* p = ksb + (size_t)b * NCn * 128 + i;
        float run = 0.f;
        for (int g = 0; g < 4; ++g) {
            float buf[16];
#pragma unroll
            for (int j = 0; j < 16; ++j) buf[j] = p[(size_t)(g * 16 + j) * 128];
#pragma unroll
            for (int j = 0; j < 16; ++j) {
                p[(size_t)(g * 16 + j) * 128] = run;
                run += buf[j];
            }
        }
    }
}

// out = (Q @ S_prefix + Sc @ V) / den
__device__ __forceinline__ void out_phase(
    const float* __restrict__ qb, const float* __restrict__ vb,
    const float* __restrict__ kvb, const float* __restrict__ ksb,
    const float* __restrict__ scb, const float* __restrict__ rsb,
    float* __restrict__ out, float* smem, int cb, int ch)
{
    float* sQ  = smem;           // 32*132 = 4224
    float* sVs = smem + 4224;    // 32*36  = 1152
    float* sSc = smem + 5376;    // 32*36  = 1152
    float* sKp = smem + 6528;    // 128
    float* sDen = smem + 6656;   // 32

    const int tid = threadIdx.x;

    {
        const float4* qg = (const float4*)(qb + (size_t)cb * 4096);
#pragma unroll
        for (int i = 0; i < 4; ++i) {
            int idx = tid + i * 256;
            int r = idx >> 5, c4 = idx & 31;
            *(float4*)&sQ[r * 132 + c4 * 4] = qg[idx];
        }
        {
            int r = tid >> 3, c4 = tid & 7;
            *(float4*)&sVs[r * 36 + c4 * 4] =
                *(const float4*)(vb + (size_t)cb * 4096 + r * 128 + ch * 32 + c4 * 4);
            *(float4*)&sSc[r * 36 + c4 * 4] =
                *(const float4*)(scb + (size_t)cb * 1024 + tid * 4);
        }
        if (tid < 128) sKp[tid] = ksb[cb * 128 + tid];
    }
    __syncthreads();

    if (tid < 32) {
        float d = 0.f;
#pragma unroll
        for (int k4 = 0; k4 < 32; ++k4) {
            float4 a  = *(const float4*)&sQ[tid * 132 + k4 * 4];
            float4 b2 = *(const float4*)&sKp[k4 * 4];
            d += a.x * b2.x + a.y * b2.y + a.z * b2.z + a.w * b2.w;
        }
        sDen[tid] = d + rsb[cb * 32 + tid] + 1e-6f;
    }

    const int row = tid >> 3;
    const int c4  = tid & 7;
    const float* Sg = kvb + (size_t)cb * 16384 + ch * 32 + c4 * 4;

    float a0 = 0.f, a1 = 0.f, a2 = 0.f, a3 = 0.f;
#pragma unroll 8
    for (int k = 0; k < 128; ++k) {
        const float qv = sQ[row * 132 + k];
        float4 s = *(const float4*)(Sg + (size_t)k * 128);
        a0 += qv * s.x; a1 += qv * s.y; a2 += qv * s.z; a3 += qv * s.w;
    }
#pragma unroll 8
    for (int tp = 0; tp < 32; ++tp) {
        const float sc = sSc[row * 36 + tp];
        float4 v = *(const float4*)&sVs[tp * 36 + c4 * 4];
        a0 += sc * v.x; a1 += sc * v.y; a2 += sc * v.z; a3 += sc * v.w;
    }
    __syncthreads();

    const float dv = sDen[row];
    *(float4*)(out + ((size_t)cb * 32 + row) * 128 + ch * 32 + c4 * 4) =
        make_float4(a0 / dv, a1 / dv, a2 / dv, a3 / dv);
}

// ===========================================================================
// Fused kernel: plain launch, grid 1024 x 256, 4 blocks/CU (guaranteed by
// launch_bounds(256,4) VGPR cap + 38.4 KB LDS), low-contention grid barriers.
// ===========================================================================
__global__ __launch_bounds__(256, 4) void fused_kernel(
    const float* __restrict__ x, const float* __restrict__ W,
    const float* __restrict__ bias,
    float* __restrict__ qb, float* __restrict__ kb, float* __restrict__ vb,
    float* __restrict__ kvb, float* __restrict__ ksb,
    float* __restrict__ scb, float* __restrict__ rsb,
    float* __restrict__ out, unsigned* __restrict__ bar)
{
    __shared__ __align__(16) float smem[9600];   // 38.4 KB (union of phases)
    const int blk = blockIdx.x;

    if (blk < 768)
        qkv_phase(x, W, bias, qb, kb, vb, smem, smem + 2304,
                  (blk & 127) * 64, (blk >> 7) * 64);
    grid_barrier(bar, 64u, blk);           // 16 counters @ bar[0..255]

    cs_phase(qb, kb, vb, kvb, ksb, scb, rsb, smem, blk);
    grid_barrier(bar + 256, 64u, blk);     // 16 counters @ bar[256..511]

    prefix_phase(kvb, ksb, blk);
    grid_barrier(bar + 512, 64u, blk);     // 16 counters @ bar[512..767]

    out_phase(qb, vb, kvb, ksb, scb, rsb, out, smem, blk >> 2, blk & 3);
}

// ===========================================================================
extern "C" void kernel_launch(void* const* d_in, const int* in_sizes, int n_in,
                              void* d_out, int out_size, void* d_ws, size_t ws_size,
                              hipStream_t stream)
{
    const float* x    = (const float*)d_in[0];   // (B,T,D)
    const float* W    = (const float*)d_in[1];   // (3D, D)
    const float* bias = (const float*)d_in[2];   // (3D,)
    float* out = (float*)d_out;                  // (B,T,D)

    float* ws  = (float*)d_ws;
    float* qb  = ws;                       // 1,048,576 floats
    float* kb  = ws + 1048576;             // 1,048,576
    float* vb  = ws + 2097152;             // 1,048,576
    float* kvb = ws + 3145728;             // 4,194,304
    float* ksb = ws + 7340032;             // 32,768
    float* scb = ws + 7372800;             // 262,144
    float* rsb = ws + 7634944;             // 8,192
    unsigned* bar = (unsigned*)(ws + 7643136);   // 3 barriers x 16 counters x 16 spacing

    hipMemsetAsync(bar, 0, 768 * sizeof(unsigned), stream);
    fused_kernel<<<1024, 256, 0, stream>>>(x, W, bias, qb, kb, vb, kvb, ksb,
                                           scb, rsb, out, bar);
}